// Round 4
// baseline (48.502 us; speedup 1.0000x reference)
//
#include <hip/hip_runtime.h>
#include <math.h>

constexpr int N_ITEMS = 512;
constexpr int TS      = 2048;    // TABLE_SAMPLES
constexpr int FULL    = 32768;
constexpr int PADDED  = 65536;
constexpr int NPAIR   = 512;     // BATCH * N_EVENTS
constexpr int NMM     = 64;      // min/max partial blocks (= one wave's lanes)

using f4 = __attribute__((ext_vector_type(4))) float;

// ---- order-preserving float <-> uint encoding for min/max over partials ----
__device__ __forceinline__ unsigned fenc(float f) {
    unsigned u = __float_as_uint(f);
    return (u & 0x80000000u) ? ~u : (u | 0x80000000u);
}
__device__ __forceinline__ float fdec(unsigned e) {
    return __uint_as_float((e & 0x80000000u) ? (e & 0x7FFFFFFFu) : ~e);
}

// ws layout (bytes):
//   [0    ..  255]  min partials, unsigned[64]
//   [256  ..  511]  max partials, unsigned[64]
//   [512  .. 2559]  idx, int[512]
//   [2560 .. 4607]  w,   float[512]

// k_prep, grid = 192 x 256:
//   blocks 0..63   : min/max partials over 1/64 of the items table
//   blocks 64..191 : sparse-softmax selection, 4 pairs per block (1 wave each)
__global__ void __launch_bounds__(256) k_prep(const f4* __restrict__ items4,
                                              const float* __restrict__ sel,
                                              unsigned* __restrict__ ws_min,
                                              unsigned* __restrict__ ws_max,
                                              int* __restrict__ ws_idx,
                                              float* __restrict__ ws_w) {
    __shared__ unsigned smin[4], smax[4];
    int blk = blockIdx.x;
    int tid = threadIdx.x;

    if (blk < NMM) {
        unsigned lmin = 0xFFFFFFFFu, lmax = 0u;
        const int NV = (N_ITEMS * TS) / 4;              // 262144 float4
        for (int i = blk * 256 + tid; i < NV; i += NMM * 256) {   // 16 iters
            f4 v = items4[i];
            unsigned e0 = fenc(v.x), e1 = fenc(v.y), e2 = fenc(v.z), e3 = fenc(v.w);
            lmin = min(min(min(lmin, e0), min(e1, e2)), e3);
            lmax = max(max(max(lmax, e0), max(e1, e2)), e3);
        }
        for (int off = 32; off > 0; off >>= 1) {
            lmin = min(lmin, (unsigned)__shfl_xor((int)lmin, off));
            lmax = max(lmax, (unsigned)__shfl_xor((int)lmax, off));
        }
        int wave = tid >> 6;
        if ((tid & 63) == 0) { smin[wave] = lmin; smax[wave] = lmax; }
        __syncthreads();
        if (tid == 0) {
            ws_min[blk] = min(min(smin[0], smin[1]), min(smin[2], smin[3]));
            ws_max[blk] = max(max(smax[0], smax[1]), max(smax[2], smax[3]));
        }
    } else {
        int p    = (blk - NMM) * 4 + (tid >> 6);
        int lane = tid & 63;
        const float* s = sel + (size_t)p * N_ITEMS;
        float x[8];
        float vmax = -INFINITY;
        int   imax = 0x7FFFFFFF;
        #pragma unroll
        for (int k = 0; k < 8; ++k) {
            int i = lane + k * 64;
            x[k] = s[i];
            if (x[k] > vmax) { vmax = x[k]; imax = i; }  // ascending -> first occurrence
        }
        for (int off = 32; off > 0; off >>= 1) {
            float ov = __shfl_xor(vmax, off);
            int   oi = __shfl_xor(imax, off);
            if (ov > vmax || (ov == vmax && oi < imax)) { vmax = ov; imax = oi; }
        }
        float se = 0.0f;
        #pragma unroll
        for (int k = 0; k < 8; ++k) se += expf(x[k] - vmax);
        for (int off = 32; off > 0; off >>= 1) se += __shfl_xor(se, off);
        if (lane == 0) { ws_idx[p] = imax; ws_w[p] = 1.0f / se; }
    }
}

// k_main, grid = 1024 x 256: block = (pair, half). NO LDS, NO barriers.
// Normalization is affine and commutes with lerp, so we interp RAW item
// values straight from global (8 KB row, L1-hot) and fold the affine after.
// Per float4 of output, lo spans at most {lo0, lo0+1}: 3 cached row loads.
__global__ void __launch_bounds__(256) k_main(const float* __restrict__ items,
                                              const float* __restrict__ noise,
                                              const unsigned* __restrict__ ws_min,
                                              const unsigned* __restrict__ ws_max,
                                              const int* __restrict__ ws_idx,
                                              const float* __restrict__ ws_w,
                                              float* __restrict__ out) {
    int blk = blockIdx.x;
    int p   = blk >> 1;
    int q   = blk & 1;
    int tid = threadIdx.x;
    int lane = tid & 63;

    // wave-independent reduce of the 64 min/max partials (no barrier needed)
    unsigned lmin = ws_min[lane], lmax = ws_max[lane];
    for (int off = 32; off > 0; off >>= 1) {
        lmin = min(lmin, (unsigned)__shfl_xor((int)lmin, off));
        lmax = max(lmax, (unsigned)__shfl_xor((int)lmax, off));
    }
    float minv  = fdec(lmin);
    float maxv  = fdec(lmax);
    float denom = (maxv - minv) + 0.001f;
    int   idx   = ws_idx[p];
    float w     = ws_w[p];
    float scale = w / denom;
    float bias  = -minv * scale;

    const float* g = items + (size_t)idx * TS;

    constexpr int CHUNK = FULL / 2;   // 16384
    const f4* nz4  = (const f4*)(noise + (size_t)p * FULL + (size_t)q * CHUNK);
    f4*       o4   = (f4*)(out + (size_t)p * PADDED + (size_t)q * CHUNK);
    f4*       pad4 = (f4*)(out + (size_t)p * PADDED + FULL + (size_t)q * CHUNK);
    int tbase = q * CHUNK;

    f4 z = {0.f, 0.f, 0.f, 0.f};
    for (int v = tid; v < CHUNK / 4; v += 256) {     // 16 iters
        f4 nz = __builtin_nontemporal_load(&nz4[v]);
        int t0 = tbase + v * 4;
        float pos0  = ((float)t0 + 0.5f) * 0.0625f - 0.5f;
        float pos0c = fminf(fmaxf(pos0, 0.0f), (float)(TS - 1));
        int lo0 = (int)pos0c;                        // trunc == floor (>=0)
        float a = g[lo0];
        float b = g[min(lo0 + 1, TS - 1)];
        float c = g[min(lo0 + 2, TS - 1)];
        f4 o;
        #pragma unroll
        for (int j = 0; j < 4; ++j) {
            float pj = fminf(fmaxf(pos0 + (float)j * 0.0625f, 0.0f), (float)(TS - 1));
            int   lj = (int)pj;
            float fr = pj - (float)lj;
            bool  cr = lj > lo0;                     // lo_j in {lo0, lo0+1}
            float va = cr ? b : a;
            float vb = cr ? c : b;
            float raw = fmaf(fr, vb - va, va);       // lerp of raw values
            o[j] = fmaf(raw, scale, bias) * nz[j];   // affine after lerp
        }
        __builtin_nontemporal_store(o, &o4[v]);
        __builtin_nontemporal_store(z, &pad4[v]);
    }
}

extern "C" void kernel_launch(void* const* d_in, const int* in_sizes, int n_in,
                              void* d_out, int out_size, void* d_ws, size_t ws_size,
                              hipStream_t stream) {
    const float* sel   = (const float*)d_in[0];   // [8,64,512]
    const float* items = (const float*)d_in[1];   // [512,2048]
    const float* noise = (const float*)d_in[2];   // [8,64,32768]
    float* out = (float*)d_out;                   // [8,64,65536]

    unsigned* ws_min = (unsigned*)d_ws;
    unsigned* ws_max = (unsigned*)((char*)d_ws + 256);
    int*      ws_idx = (int*)((char*)d_ws + 512);
    float*    ws_w   = (float*)((char*)d_ws + 2560);

    hipLaunchKernelGGL(k_prep, dim3(NMM + NPAIR / 4), dim3(256), 0, stream,
                       (const f4*)items, sel, ws_min, ws_max, ws_idx, ws_w);
    hipLaunchKernelGGL(k_main, dim3(NPAIR * 2), dim3(256), 0, stream,
                       items, noise, ws_min, ws_max, ws_idx, ws_w, out);
}